// Round 9
// baseline (3313.905 us; speedup 1.0000x reference)
//
#include <hip/hip_runtime.h>

// NDDE forward-Euler, d=512, N=2000 — latency-bound on the per-step x
// all-to-all through the MALL (agent atomics, R1/R4/R5-proven). R9 theory:
// the R5/R7/R8 plateau (~1.43us/step) is VMCNT IN-ORDER COUPLING — the
// critical path drains publish-ACK, history loads, and out-store ACKs
// because vmcnt retires in order. Fix: polls are the only VMEM the
// critical path waits on.
//   1. Pre-issue next-slot polls BEFORE the publish store (vmcnt(k) then
//      skips the younger store). Own records can't be fresh -> skip their
//      tag check, substitute own values via __shfl (always correct).
//   2. y path via a 101-deep LDS queue of fully-reduced q_j = W2*x_j
//      (computed in the shadow from registers): zero VMEM, lgkmcnt only.
//   3. out stores batched 16 steps (shift register) -> 15/16 steps have
//      no out VMEM.

#define D    512
#define NTAU 100
#define M    112        // ring depth > delay span 101 + skew
#define QD   101        // LDS ydot queue depth
#define NW   64         // waves; wave w owns rows 8w..8w+7

typedef unsigned long long u64;

__device__ __forceinline__ float lo_f(u64 v){ union{unsigned u; float f;} c; c.u=(unsigned)v; return c.f; }
__device__ __forceinline__ u64 pack_rec(unsigned tag, float x){ union{unsigned u; float f;} c; c.f=x; return ((u64)tag<<32)|(u64)c.u; }
__device__ __forceinline__ u64 ag_ld(const u64* p){
    return __hip_atomic_load(p, __ATOMIC_RELAXED, __HIP_MEMORY_SCOPE_AGENT);
}
__device__ __forceinline__ void ag_st(u64* p, u64 v){
    __hip_atomic_store(p, v, __ATOMIC_RELAXED, __HIP_MEMORY_SCOPE_AGENT);
}
__device__ __forceinline__ void iss8(const u64* p, u64 r[8]){
    #pragma unroll
    for (int i = 0; i < 8; ++i) r[i] = ag_ld(p + 64 * i);
}
// tag check skipping own records (i==i0 && lane in own 8-lane span)
__device__ __forceinline__ bool chk8m(const u64 r[8], unsigned t, int i0, bool ownm){
    bool ok = true;
    #pragma unroll
    for (int i = 0; i < 8; ++i)
        ok &= (((unsigned)(r[i] >> 32) == t) || (ownm && i == i0));
    return __all(ok);
}
__device__ __forceinline__ float sel8(const float* a, int k){
    float s = a[0];
    s = (k == 1) ? a[1] : s;  s = (k == 2) ? a[2] : s;
    s = (k == 3) ? a[3] : s;  s = (k == 4) ? a[4] : s;
    s = (k == 5) ? a[5] : s;  s = (k == 6) ? a[6] : s;
    s = (k == 7) ? a[7] : s;
    return s;
}
// full 64-lane reduce of 8 chains -> lane r (r<8) holds total of chain r
__device__ __forceinline__ float reduce8(float a[8], int sel){
    #pragma unroll
    for (int r = 0; r < 8; ++r){
        a[r] += __shfl_xor(a[r], 1, 64);
        a[r] += __shfl_xor(a[r], 2, 64);
        a[r] += __shfl_xor(a[r], 4, 64);
    }
    float d = sel8(a, sel);
    d += __shfl_xor(d, 8, 64);
    d += __shfl_xor(d, 16, 64);
    d += __shfl_xor(d, 32, 64);
    return d;
}

__global__ __launch_bounds__(64)
__attribute__((amdgpu_waves_per_eu(1, 1)))
void ndde_r9(
    const float* __restrict__ x0p, const float* __restrict__ taup,
    const float* __restrict__ W1,  const float* __restrict__ W2,
    const float* __restrict__ bb,  const int* __restrict__ Np,
    float* __restrict__ out, u64* __restrict__ ring, float one)
{
    __shared__ float qlds[QD * 8];          // 3.2 KB ydot queue (single wave: no barriers)

    const int lane    = threadIdx.x & 63;
    const int wb      = blockIdx.x;         // 0..63
    const int rowbase = wb * 8;
    const int N       = Np[0];
    const float dt    = 0.01f * taup[0];
    const int sel     = lane & 7;
    const int i0      = wb >> 3;            // chunk holding own rows
    const int lb      = (wb * 8) & 63;      // first own lane in that chunk
    const bool ownm   = ((unsigned)(lane - lb)) < 8u;

    // ---- weights: 8 rows x 8 strided cols; opaque-scaled + pinned ----
    float w1v[8][8], w2v[8][8];
    #pragma unroll
    for (int r = 0; r < 8; ++r){
        const float* p1 = W1 + (size_t)(rowbase + r) * D + lane;
        const float* p2 = W2 + (size_t)(rowbase + r) * D + lane;
        #pragma unroll
        for (int i = 0; i < 8; ++i){
            w1v[r][i] = p1[64 * i] * one;
            w2v[r][i] = p2[64 * i] * one;
        }
    }
    #pragma unroll
    for (int r = 0; r < 8; ++r){
        #pragma unroll
        for (int i = 0; i < 8; ++i)
            asm volatile("" : "+v"(w1v[r][i]), "+v"(w2v[r][i]));
    }

    // ---- prologue: x0 partials, q0 = W2*x0 (reduced), step 0 local ----
    float xv0[8];
    #pragma unroll
    for (int i = 0; i < 8; ++i) xv0[i] = x0p[64 * i + lane];
    float ax[8], ay[8];
    #pragma unroll
    for (int r = 0; r < 8; ++r){
        float st = 0.f, sy = 0.f;
        #pragma unroll
        for (int i = 0; i < 8; ++i){
            st = fmaf(w1v[r][i], xv0[i], st);
            sy = fmaf(w2v[r][i], xv0[i], sy);
        }
        ax[r] = st; ay[r] = sy;
    }
    const float xdot0 = reduce8(ax, sel);
    const float q0    = reduce8(ay, sel);   // lane r: full W2*x0 dot of row r
    if (lane < 8) qlds[0 * 8 + lane] = q0;

    float xloc = 0.f, bval = 0.f;
    if (lane < 8){
        const int row = rowbase + lane;
        xloc = x0p[row];
        bval = bb[row];
        out[(size_t)row * (N + 1)] = xloc;
        if (N >= 1){
            const float x1 = xloc + dt * tanhf(xdot0 + q0 + bval);
            xloc = x1;
            ag_st(ring + D + row, pack_rec(2u, x1));
            out[(size_t)row * (N + 1) + 1] = x1;
        }
    }

    // ---- initial poll issue for slot 1 ----
    u64 cur[8];
    iss8(ring + (size_t)1 * D + lane, cur);

    float obuf[16];
    #pragma unroll
    for (int k = 0; k < 16; ++k) obuf[k] = 0.f;

    int sx = 1, sp = 2;        // ring slots: j%M, (j+1)%M
    int qw = 1, qr = 0;        // LDS queue write/read slots
    bool dead = false;

    for (int j = 1; j < N && !dead; ++j){
        const unsigned tx = (unsigned)(j + 1);
        const u64* px = ring + (size_t)sx * D + lane;

        // ---- early LDS read of ydot (lgkmcnt, decoupled from VMEM) ----
        float ydot = 0.f;
        if (lane < 8) ydot = qlds[qr * 8 + lane];

        // ---- check pre-issued batch; spin depth-2 if not ready ----
        if (!chk8m(cur, tx, i0, ownm)){
            u64 alt[8];
            iss8(px, alt);
            int it = 0;
            for (;;){
                iss8(px, cur);
                if (chk8m(alt, tx, i0, ownm)){
                    #pragma unroll
                    for (int i = 0; i < 8; ++i) cur[i] = alt[i];
                    break;
                }
                iss8(px, alt);
                if (chk8m(cur, tx, i0, ownm)) break;
                if ((it += 2) > (1 << 21)){ dead = true; break; }
            }
        }
        float xf[8];
        #pragma unroll
        for (int i = 0; i < 8; ++i) xf[i] = lo_f(cur[i]);
        // own rows: substitute locally-known values (can't be fresh in memory)
        {
            const float xsub = __shfl(xloc, lane - lb, 64);
            #pragma unroll
            for (int i = 0; i < 8; ++i)
                xf[i] = (ownm && i == i0) ? xsub : xf[i];
        }

        // ---- critical path: x-dot + reduce + integrate ----
        float a[8];
        #pragma unroll
        for (int r = 0; r < 8; ++r){
            float s = 0.f;
            #pragma unroll
            for (int i = 0; i < 8; ++i) s = fmaf(w1v[r][i], xf[i], s);
            a[r] = s;
        }
        const float xdot = reduce8(a, sel);

        float xn = 0.f;
        if (lane < 8){
            xn = xloc + dt * tanhf(xdot + ydot + bval);
            xloc = xn;
        }

        // ---- pre-issue next-slot polls BEFORE the publish store ----
        iss8(ring + (size_t)sp * D + lane, cur);
        if (lane < 8)
            ag_st(ring + (size_t)sp * D + (rowbase + lane), pack_rec(tx + 1, xn));

        // ---- shadow (VALU/LDS only): q_j = W2*x_j, obuf ----
        float c[8];
        #pragma unroll
        for (int r = 0; r < 8; ++r){
            float s = 0.f;
            #pragma unroll
            for (int i = 0; i < 8; ++i) s = fmaf(w2v[r][i], xf[i], s);
            c[r] = s;
        }
        const float qj = reduce8(c, sel);
        if (lane < 8) qlds[qw * 8 + lane] = qj;

        if (lane < 8){
            #pragma unroll
            for (int k = 0; k < 15; ++k) obuf[k] = obuf[k + 1];
            obuf[15] = xn;
            if (((j - 1) & 15) == 15){          // holds cols j-14..j+1
                float* po = out + (size_t)(rowbase + lane) * (N + 1) + (j - 14);
                #pragma unroll
                for (int k = 0; k < 16; ++k) po[k] = obuf[k];
            }
        }

        sx = sp;
        sp = (sp == M - 1) ? 0 : sp + 1;
        qw = (qw == QD - 1) ? 0 : qw + 1;
        if (j >= NTAU) qr = (qr == QD - 1) ? 0 : qr + 1;
    }

    // ---- tail flush (R8-proven logic) ----
    if (N >= 2 && lane < 8){
        const int cnt = ((N - 2) & 15) + 1;     // values since last flush
        float* po = out + (size_t)(rowbase + lane) * (N + 1);
        #pragma unroll
        for (int k = 0; k < 16; ++k){
            if (k >= 16 - cnt) po[N - 15 + k] = obuf[k];
        }
    }
}

extern "C" void kernel_launch(void* const* d_in, const int* in_sizes, int n_in,
                              void* d_out, int out_size, void* d_ws, size_t ws_size,
                              hipStream_t stream)
{
    const float* x0  = (const float*)d_in[0];
    const float* tau = (const float*)d_in[1];
    const float* W1  = (const float*)d_in[2];
    const float* W2  = (const float*)d_in[3];
    const float* b   = (const float*)d_in[4];
    const int*   Np  = (const int*)  d_in[5];

    // d_ws: ring only, M*D*8 = 448 KB. No memset: tags 1..N+1 never match
    // the 0xAA poison.
    u64* ring = (u64*)d_ws;
    const float one = 1.0f;

    hipLaunchKernelGGL(ndde_r9, dim3(NW), dim3(64), 0, stream,
                       x0, tau, W1, W2, b, Np, (float*)d_out, ring, one);
}